// Round 6
// baseline (212.496 us; speedup 1.0000x reference)
//
#include <hip/hip_runtime.h>
#include <hip/hip_bf16.h>
#include <math.h>

using bf16 = __hip_bfloat16;

typedef __attribute__((ext_vector_type(4))) float fv4;
typedef __attribute__((ext_vector_type(4))) short sh4;
typedef __attribute__((ext_vector_type(8))) short sh8;
typedef __attribute__((ext_vector_type(4))) float f4acc;

#define T_TOK 2048
#define HD    1024
#define NE    16
#define KD    1024
#define NPAIR 8192

// ---- workspace layout (bytes), lifetime-aliased; peak 66.2 MB ----
static constexpr size_t OFF_XB   = 0;          // bf16 xb [2048][1024] (K1-K2); act (K3-K4)
static constexpr size_t OFF_GUB  = 4194304;    // bf16 gu [2048][2048] (K2-K3)
static constexpr size_t OFF_H1   = 12582912;   // bf16 h1 [8192][1024] (K2-K4)
static constexpr size_t OFF_W1B  = 29360128;   // bf16 w1 [16][1024][1024] (K1-K2); w2b (K3-K4)
static constexpr size_t OFF_SGUB = 62914560;   // bf16 sgu [2048][1024] (K1-K2)
static constexpr size_t OFF_SDNB = 67108864;   // bf16 sdn [1024][1024] (K1-K4)
static constexpr size_t OFF_TOPI = 69206016;   // int  [8192]
static constexpr size_t OFF_TOPV = 69238784;   // f32  [8192]
static constexpr size_t OFF_PTOK = 69271552;   // int  [8192]
static constexpr size_t OFF_PWT  = 69304320;   // f32  [8192]
static constexpr size_t OFF_OFFS = 69337088;   // int  [17]

__device__ __forceinline__ short f2bf(float f) {
  __hip_bfloat16 h = __float2bfloat16(f);
  union { __hip_bfloat16 b; short s; } u; u.b = h; return u.s;
}
__device__ __forceinline__ float bf2f(short s) {
  union { unsigned u; float f; } c; c.u = ((unsigned)(unsigned short)s) << 16; return c.f;
}
__device__ __forceinline__ void async16(const void* g, void* l) {
  __builtin_amdgcn_global_load_lds(
      (const __attribute__((address_space(1))) void*)g,
      (__attribute__((address_space(3))) void*)l, 16, 0, 0);
}

// ---------- K1: cast x, w1, sgu, sdn (fp32 -> bf16), one fv4/thread ----------
__global__ __launch_bounds__(256) void cast_all_kernel(const float* __restrict__ x,
                                                       const float* __restrict__ w1,
                                                       const float* __restrict__ sgu,
                                                       const float* __restrict__ sdn,
                                                       short* __restrict__ xb,
                                                       short* __restrict__ w1b,
                                                       short* __restrict__ sgub,
                                                       short* __restrict__ sdnb) {
  int bid = blockIdx.x;
  const float* src; short* dst; int idx;
  if (bid < 2048)        { src = x;   dst = xb;   idx = bid * 256 + threadIdx.x; }
  else if (bid < 18432)  { src = w1;  dst = w1b;  idx = (bid - 2048) * 256 + threadIdx.x; }
  else if (bid < 20480)  { src = sgu; dst = sgub; idx = (bid - 18432) * 256 + threadIdx.x; }
  else                   { src = sdn; dst = sdnb; idx = (bid - 20480) * 256 + threadIdx.x; }
  fv4 v = ((const fv4*)src)[idx];
  sh4 o; o[0]=f2bf(v[0]); o[1]=f2bf(v[1]); o[2]=f2bf(v[2]); o[3]=f2bf(v[3]);
  ((sh4*)dst)[idx] = o;
}

// ---------- router: NO atomics; gw in LDS, branchless register top-4 ----------
__global__ __launch_bounds__(256) void router_kernel(const float* __restrict__ x,
                                                     const float* __restrict__ gw,
                                                     int* __restrict__ topi,
                                                     float* __restrict__ topv) {
  __shared__ float gsh[NE * HD];  // 64 KiB
  const int tid = threadIdx.x;
  const int wave = tid >> 6;
  const int lane = tid & 63;
  const int t = blockIdx.x * 4 + wave;

#pragma unroll
  for (int r = 0; r < 16; ++r) {
    int idx = r * 256 + tid;
    ((fv4*)gsh)[idx] = ((const fv4*)gw)[idx];
  }

  const float* xr = x + (size_t)t * HD;
  fv4 xa[4];
#pragma unroll
  for (int q = 0; q < 4; ++q) xa[q] = *(const fv4*)(xr + q * 256 + lane * 4);

  __syncthreads();

  float p[NE];
#pragma unroll
  for (int e = 0; e < NE; ++e) {
    const float* g = gsh + e * HD;
    float a = 0.f;
#pragma unroll
    for (int q = 0; q < 4; ++q) {
      fv4 gv = *(const fv4*)(g + q * 256 + lane * 4);
      a += xa[q][0] * gv[0] + xa[q][1] * gv[1] + xa[q][2] * gv[2] + xa[q][3] * gv[3];
    }
    p[e] = a;
  }
#pragma unroll
  for (int off = 1; off < 64; off <<= 1) {
#pragma unroll
    for (int e = 0; e < NE; ++e) p[e] += __shfl_xor(p[e], off);
  }

  int sel_i[4]; float sel_v[4];
#pragma unroll
  for (int k = 0; k < 4; ++k) {
    float best = p[0]; int bi = 0;
#pragma unroll
    for (int e = 1; e < NE; ++e) {
      bool c = p[e] > best;
      best = c ? p[e] : best;
      bi   = c ? e : bi;
    }
    sel_i[k] = bi; sel_v[k] = best;
#pragma unroll
    for (int e = 0; e < NE; ++e) p[e] = (e == bi) ? -3.4e38f : p[e];
  }
  float m = sel_v[0];
  float e0 = expf(sel_v[0] - m), e1 = expf(sel_v[1] - m);
  float e2 = expf(sel_v[2] - m), e3 = expf(sel_v[3] - m);
  float inv = 1.f / (e0 + e1 + e2 + e3);

  if (lane == 0) {
    topi[t * 4 + 0] = sel_i[0]; topv[t * 4 + 0] = e0 * inv;
    topi[t * 4 + 1] = sel_i[1]; topv[t * 4 + 1] = e1 * inv;
    topi[t * 4 + 2] = sel_i[2]; topv[t * 4 + 2] = e2 * inv;
    topi[t * 4 + 3] = sel_i[3]; topv[t * 4 + 3] = e3 * inv;
  }
}

// ---------- route build: ballot-based; emits pair_token + pair_weight ----------
__global__ __launch_bounds__(1024) void route_build_kernel(const int* __restrict__ topi,
                                                           const float* __restrict__ topv,
                                                           int* __restrict__ offsets,
                                                           int* __restrict__ pair_token,
                                                           float* __restrict__ pair_weight) {
  __shared__ int tsh[NPAIR];
  __shared__ int cnt_sh[NE];
  __shared__ int off_sh[NE + 1];
  const int tid = threadIdx.x;
  const int wave = tid >> 6;
  const int lane = tid & 63;

#pragma unroll
  for (int r = 0; r < NPAIR / 1024; ++r) tsh[r * 1024 + tid] = topi[r * 1024 + tid];
  __syncthreads();

  const int e = wave;
  int cnt = 0;
  for (int c = 0; c < NPAIR; c += 64) {
    unsigned long long msk = __ballot(tsh[c + lane] == e);
    cnt += __popcll(msk);
  }
  if (lane == 0) cnt_sh[e] = cnt;
  __syncthreads();
  if (tid == 0) {
    int acc = 0;
    for (int i = 0; i < NE; ++i) { off_sh[i] = acc; acc += cnt_sh[i]; }
    off_sh[NE] = acc;
  }
  __syncthreads();
  if (tid <= NE) offsets[tid] = off_sh[tid];

  int base = off_sh[e];
  for (int c = 0; c < NPAIR; c += 64) {
    bool match = (tsh[c + lane] == e);
    unsigned long long msk = __ballot(match);
    unsigned long long lt = (lane == 0) ? 0ull : ((~0ull) >> (64 - lane));
    int pre = __popcll(msk & lt);
    if (match) {
      int slot = base + pre;
      pair_token[slot] = (c + lane) >> 2;
      pair_weight[slot] = topv[c + lane];
    }
    base += __popcll(msk);
  }
}

// ---------- K3: cast w2 + shared-expert activation ----------
__global__ __launch_bounds__(256) void act_w2_kernel(const float* __restrict__ w2,
                                                     short* __restrict__ w2b,
                                                     const short* __restrict__ gub,
                                                     short* __restrict__ act) {
  int bid = blockIdx.x;
  if (bid < 16384) {
    int idx = bid * 256 + threadIdx.x;
    fv4 v = ((const fv4*)w2)[idx];
    sh4 o; o[0]=f2bf(v[0]); o[1]=f2bf(v[1]); o[2]=f2bf(v[2]); o[3]=f2bf(v[3]);
    ((sh4*)w2b)[idx] = o;
  } else {
    int i = (bid - 16384) * 256 + threadIdx.x;  // 2048*256, 4 elems each
    int t = i >> 8, g = i & 255;
    sh4 gs = *(const sh4*)(gub + (size_t)t * 2048 + g * 4);
    sh4 us = *(const sh4*)(gub + (size_t)t * 2048 + 1024 + g * 4);
    sh4 o;
#pragma unroll
    for (int q = 0; q < 4; ++q) {
      float gg = bf2f(gs[q]);
      float s = gg / (1.f + expf(-gg)) * bf2f(us[q]);
      o[q] = f2bf(s);
    }
    *(sh4*)(act + (size_t)t * 1024 + g * 4) = o;
  }
}

// ---------- paired GEMM, all-bf16, all-async16 staging, dbuf pipeline ----------
// PHASE 0: routed H1 (A=xb gathered, B=w1b, out=silu->h1 bf16)
//          + shared GU (A=xb, B=sgub N=2048, out=gu bf16 stride 2048)
// PHASE 1: routed Y  (A=h1 slots, B=w2b, out=atomicAdd weighted into d_out)
//          + shared DOWN (A=act, B=sdnb N=1024, out=atomicAdd into d_out)
template <int PHASE>
__global__ __launch_bounds__(256) void gemm_pair_kernel(
    const bf16* __restrict__ A_sh, const bf16* __restrict__ A_rt,
    const bf16* __restrict__ B_sh, const bf16* __restrict__ B_rt,
    void* __restrict__ O_sh, void* __restrict__ O_rt,
    const int* __restrict__ ptok, const float* __restrict__ pwt,
    const int* __restrict__ offsets) {
  __shared__ bf16 Ash[2][128][32];
  __shared__ bf16 Bsh[2][128][32];

  const int tid = threadIdx.x;
  const int lane = tid & 63;
  const int wave = tid >> 6;
  const int wm = wave >> 1, wn = wave & 1;

  const bool routed = (int)blockIdx.x < 2048;
  int mt, nt, seg_start = 0, count = 0;
  const bf16* Abase;
  const bf16* Bpanel;
  if (routed) {
    int bid = blockIdx.x;
    int e = bid & 15;
    int r = bid >> 4;            // [0,128)
    mt = r >> 3; nt = r & 7;
    seg_start = offsets[e];
    count = offsets[e + 1] - seg_start;
    if (mt * 128 >= count) return;
    Abase = A_rt;
    Bpanel = B_rt + ((size_t)e << 20) + (size_t)(nt * 128) * KD;
  } else {
    int sb = blockIdx.x - 2048;
    constexpr int nwg = (PHASE == 0) ? 256 : 128;
    constexpr int cpx = nwg >> 3;
    int sw = (sb & 7) * cpx + (sb >> 3);
    nt = sw >> 4; mt = sw & 15;
    count = 1 << 30;
    Abase = A_sh;
    Bpanel = B_sh + (size_t)(nt * 128) * KD;
  }

  const bf16* arow[2];
  const bf16* brow[2];
#pragma unroll
  for (int r = 0; r < 2; ++r) {
    int rowloc = r * 64 + wave * 16 + (lane >> 2);
    int grow;
    if (routed) {
      int slot = seg_start + mt * 128 + rowloc;
      if (slot > NPAIR - 1) slot = NPAIR - 1;
      grow = (PHASE == 0) ? ptok[slot] : slot;
    } else {
      grow = mt * 128 + rowloc;
    }
    arow[r] = Abase + (size_t)grow * KD + (lane & 3) * 8;
    brow[r] = Bpanel + (size_t)rowloc * KD + (lane & 3) * 8;
  }

  f4acc acc[4][4];
#pragma unroll
  for (int i = 0; i < 4; ++i)
#pragma unroll
    for (int j = 0; j < 4; ++j) acc[i][j] = (f4acc)(0.f);

  // prologue: stage kt=0 into buf 0
  async16(arow[0], (void*)&Ash[0][wave * 16][0]);
  async16(arow[1], (void*)&Ash[0][64 + wave * 16][0]);
  async16(brow[0], (void*)&Bsh[0][wave * 16][0]);
  async16(brow[1], (void*)&Bsh[0][64 + wave * 16][0]);
  asm volatile("s_waitcnt vmcnt(0)" ::: "memory");
  __builtin_amdgcn_s_barrier();

  int buf = 0;
  for (int kt = 0; kt < 32; ++kt) {
    const int k0n = (kt + 1) * 32;
    if (kt < 31) {
      async16(arow[0] + k0n, (void*)&Ash[buf ^ 1][wave * 16][0]);
      async16(arow[1] + k0n, (void*)&Ash[buf ^ 1][64 + wave * 16][0]);
      async16(brow[0] + k0n, (void*)&Bsh[buf ^ 1][wave * 16][0]);
      async16(brow[1] + k0n, (void*)&Bsh[buf ^ 1][64 + wave * 16][0]);
    }

    sh8 fa[4], fb[4];
#pragma unroll
    for (int mi = 0; mi < 4; ++mi)
      fa[mi] = *(const sh8*)&Ash[buf][wm * 64 + mi * 16 + (lane & 15)][(lane >> 4) * 8];
#pragma unroll
    for (int ni = 0; ni < 4; ++ni)
      fb[ni] = *(const sh8*)&Bsh[buf][wn * 64 + ni * 16 + (lane & 15)][(lane >> 4) * 8];
#pragma unroll
    for (int mi = 0; mi < 4; ++mi)
#pragma unroll
      for (int ni = 0; ni < 4; ++ni)
        acc[mi][ni] = __builtin_amdgcn_mfma_f32_16x16x32_bf16(fa[mi], fb[ni], acc[mi][ni], 0, 0, 0);

    asm volatile("s_waitcnt vmcnt(0)" ::: "memory");
    __builtin_amdgcn_s_barrier();
    buf ^= 1;
  }

  // epilogue: C/D layout col = lane&15, row = (lane>>4)*4 + j
  if (PHASE == 0) {
    if (routed) {
#pragma unroll
      for (int mi = 0; mi < 4; ++mi) {
#pragma unroll
        for (int j = 0; j < 4; ++j) {
          int rloc = wm * 64 + mi * 16 + (lane >> 4) * 4 + j;
          if (mt * 128 + rloc >= count) continue;
          size_t orow = (size_t)(seg_start + mt * 128 + rloc) * 1024 + nt * 128;
#pragma unroll
          for (int ni = 0; ni < 4; ++ni) {
            int cloc = wn * 64 + ni * 16 + (lane & 15);
            float v = acc[mi][ni][j];
            float s = v / (1.f + expf(-v));
            ((short*)O_rt)[orow + cloc] = f2bf(s);
          }
        }
      }
    } else {
#pragma unroll
      for (int mi = 0; mi < 4; ++mi) {
#pragma unroll
        for (int j = 0; j < 4; ++j) {
          int rloc = wm * 64 + mi * 16 + (lane >> 4) * 4 + j;
          size_t orow = (size_t)(mt * 128 + rloc) * 2048 + nt * 128;
#pragma unroll
          for (int ni = 0; ni < 4; ++ni) {
            int cloc = wn * 64 + ni * 16 + (lane & 15);
            ((short*)O_sh)[orow + cloc] = f2bf(acc[mi][ni][j]);
          }
        }
      }
    }
  } else {
    if (routed) {
#pragma unroll
      for (int mi = 0; mi < 4; ++mi) {
#pragma unroll
        for (int j = 0; j < 4; ++j) {
          int rloc = wm * 64 + mi * 16 + (lane >> 4) * 4 + j;
          if (mt * 128 + rloc >= count) continue;
          int slot = seg_start + mt * 128 + rloc;
          int token = ptok[slot];
          float w = pwt[slot];
          float* orow = (float*)O_rt + (size_t)token * 1024 + nt * 128;
#pragma unroll
          for (int ni = 0; ni < 4; ++ni) {
            int cloc = wn * 64 + ni * 16 + (lane & 15);
            unsafeAtomicAdd(orow + cloc, w * acc[mi][ni][j]);
          }
        }
      }
    } else {
#pragma unroll
      for (int mi = 0; mi < 4; ++mi) {
#pragma unroll
        for (int j = 0; j < 4; ++j) {
          int rloc = wm * 64 + mi * 16 + (lane >> 4) * 4 + j;
          float* orow = (float*)O_sh + (size_t)(mt * 128 + rloc) * 1024 + nt * 128;
#pragma unroll
          for (int ni = 0; ni < 4; ++ni) {
            int cloc = wn * 64 + ni * 16 + (lane & 15);
            unsafeAtomicAdd(orow + cloc, acc[mi][ni][j]);
          }
        }
      }
    }
  }
}

extern "C" void kernel_launch(void* const* d_in, const int* in_sizes, int n_in,
                              void* d_out, int out_size, void* d_ws, size_t ws_size,
                              hipStream_t stream) {
  const float* x   = (const float*)d_in[0];
  const float* gw  = (const float*)d_in[1];
  const float* w1  = (const float*)d_in[2];
  const float* w2  = (const float*)d_in[3];
  const float* sgu = (const float*)d_in[4];
  const float* sdn = (const float*)d_in[5];
  float* out = (float*)d_out;

  char* ws = (char*)d_ws;
  bf16*  xb    = (bf16*)(ws + OFF_XB);     // aliased: act after K2
  bf16*  gub   = (bf16*)(ws + OFF_GUB);
  bf16*  h1    = (bf16*)(ws + OFF_H1);
  bf16*  w1b   = (bf16*)(ws + OFF_W1B);    // aliased: w2b after K2
  bf16*  sgub  = (bf16*)(ws + OFF_SGUB);
  bf16*  sdnb  = (bf16*)(ws + OFF_SDNB);
  int*   topi  = (int*)(ws + OFF_TOPI);
  float* topv  = (float*)(ws + OFF_TOPV);
  int*   ptok  = (int*)(ws + OFF_PTOK);
  float* pwt   = (float*)(ws + OFF_PWT);
  int*   offs  = (int*)(ws + OFF_OFFS);

  hipMemsetAsync(d_out, 0, (size_t)out_size * sizeof(float), stream);

  cast_all_kernel<<<21504, 256, 0, stream>>>(x, w1, sgu, sdn,
                                             (short*)xb, (short*)w1b,
                                             (short*)sgub, (short*)sdnb);
  router_kernel<<<512, 256, 0, stream>>>(x, gw, topi, topv);
  route_build_kernel<<<1, 1024, 0, stream>>>(topi, topv, offs, ptok, pwt);

  // K2: routed H1 (blocks 0..2047) + shared GU (2048..2303)
  gemm_pair_kernel<0><<<2304, 256, 0, stream>>>(xb, xb, sgub, w1b,
                                                gub, h1, ptok, pwt, offs);
  // K3: cast w2 (0..16383) + act (16384..18431); w2b aliases w1b region
  act_w2_kernel<<<18432, 256, 0, stream>>>(w2, (short*)w1b, (const short*)gub, (short*)xb);

  // K4: routed Y (0..2047) + shared DOWN (2048..2175); both atomicAdd into out
  gemm_pair_kernel<1><<<2176, 256, 0, stream>>>(xb /*act*/, h1, sdnb, w1b /*w2b*/,
                                                out, out, ptok, pwt, offs);
}

// Round 7
// 190.455 us; speedup vs baseline: 1.1157x; 1.1157x over previous
//
#include <hip/hip_runtime.h>
#include <hip/hip_bf16.h>
#include <math.h>

using bf16 = __hip_bfloat16;

typedef __attribute__((ext_vector_type(4))) float fv4;
typedef __attribute__((ext_vector_type(4))) short sh4;
typedef __attribute__((ext_vector_type(8))) short sh8;
typedef __attribute__((ext_vector_type(4))) float f4acc;

#define T_TOK 2048
#define HD    1024
#define NE    16
#define KD    1024
#define NPAIR 8192

// ---- workspace layout (bytes); no aliasing, peak ~34 MB ----
static constexpr size_t OFF_XB   = 0;          // bf16 xb  [2048][1024]  4 MiB
static constexpr size_t OFF_GUB  = 4194304;    // bf16 gu  [2048][2048]  8 MiB
static constexpr size_t OFF_ACT  = 12582912;   // bf16 act [2048][1024]  4 MiB
static constexpr size_t OFF_H1   = 16777216;   // bf16 h1  [8192][1024] 16 MiB
static constexpr size_t OFF_TOPI = 33554432;   // int  [8192]
static constexpr size_t OFF_TOPV = 33587200;   // f32  [8192]
static constexpr size_t OFF_PTOK = 33619968;   // int  [8192]
static constexpr size_t OFF_PWT  = 33652736;   // f32  [8192]
static constexpr size_t OFF_OFFS = 33685504;   // int  [17]

__device__ __forceinline__ short f2bf(float f) {
  __hip_bfloat16 h = __float2bfloat16(f);
  union { __hip_bfloat16 b; short s; } u; u.b = h; return u.s;
}
__device__ __forceinline__ float bf2f(short s) {
  union { unsigned u; float f; } c; c.u = ((unsigned)(unsigned short)s) << 16; return c.f;
}
__device__ __forceinline__ void async16(const void* g, void* l) {
  __builtin_amdgcn_global_load_lds(
      (const __attribute__((address_space(1))) void*)g,
      (__attribute__((address_space(3))) void*)l, 16, 0, 0);
}

// ---------- cast x (fp32 -> bf16) ----------
__global__ __launch_bounds__(256) void cast_x_kernel(const float* __restrict__ x,
                                                     bf16* __restrict__ xb) {
  int i = blockIdx.x * 256 + threadIdx.x;
  fv4 v = *(const fv4*)(x + (size_t)i * 4);
  sh4 o; o[0]=f2bf(v[0]); o[1]=f2bf(v[1]); o[2]=f2bf(v[2]); o[3]=f2bf(v[3]);
  *(sh4*)((short*)xb + (size_t)i * 4) = o;
}

// ---------- router: NO atomics; gw in LDS, branchless register top-4 ----------
__global__ __launch_bounds__(256) void router_kernel(const float* __restrict__ x,
                                                     const float* __restrict__ gw,
                                                     int* __restrict__ topi,
                                                     float* __restrict__ topv) {
  __shared__ float gsh[NE * HD];  // 64 KiB
  const int tid = threadIdx.x;
  const int wave = tid >> 6;
  const int lane = tid & 63;
  const int t = blockIdx.x * 4 + wave;

#pragma unroll
  for (int r = 0; r < 16; ++r) {
    int idx = r * 256 + tid;
    ((fv4*)gsh)[idx] = ((const fv4*)gw)[idx];
  }

  const float* xr = x + (size_t)t * HD;
  fv4 xa[4];
#pragma unroll
  for (int q = 0; q < 4; ++q) xa[q] = *(const fv4*)(xr + q * 256 + lane * 4);

  __syncthreads();

  float p[NE];
#pragma unroll
  for (int e = 0; e < NE; ++e) {
    const float* g = gsh + e * HD;
    float a = 0.f;
#pragma unroll
    for (int q = 0; q < 4; ++q) {
      fv4 gv = *(const fv4*)(g + q * 256 + lane * 4);
      a += xa[q][0] * gv[0] + xa[q][1] * gv[1] + xa[q][2] * gv[2] + xa[q][3] * gv[3];
    }
    p[e] = a;
  }
#pragma unroll
  for (int off = 1; off < 64; off <<= 1) {
#pragma unroll
    for (int e = 0; e < NE; ++e) p[e] += __shfl_xor(p[e], off);
  }

  int sel_i[4]; float sel_v[4];
#pragma unroll
  for (int k = 0; k < 4; ++k) {
    float best = p[0]; int bi = 0;
#pragma unroll
    for (int e = 1; e < NE; ++e) {
      bool c = p[e] > best;
      best = c ? p[e] : best;
      bi   = c ? e : bi;
    }
    sel_i[k] = bi; sel_v[k] = best;
#pragma unroll
    for (int e = 0; e < NE; ++e) p[e] = (e == bi) ? -3.4e38f : p[e];
  }
  float m = sel_v[0];
  float e0 = expf(sel_v[0] - m), e1 = expf(sel_v[1] - m);
  float e2 = expf(sel_v[2] - m), e3 = expf(sel_v[3] - m);
  float inv = 1.f / (e0 + e1 + e2 + e3);

  if (lane == 0) {
    topi[t * 4 + 0] = sel_i[0]; topv[t * 4 + 0] = e0 * inv;
    topi[t * 4 + 1] = sel_i[1]; topv[t * 4 + 1] = e1 * inv;
    topi[t * 4 + 2] = sel_i[2]; topv[t * 4 + 2] = e2 * inv;
    topi[t * 4 + 3] = sel_i[3]; topv[t * 4 + 3] = e3 * inv;
  }
}

// ---------- route build: ballot-based; emits pair_token + pair_weight ----------
__global__ __launch_bounds__(1024) void route_build_kernel(const int* __restrict__ topi,
                                                           const float* __restrict__ topv,
                                                           int* __restrict__ offsets,
                                                           int* __restrict__ pair_token,
                                                           float* __restrict__ pair_weight) {
  __shared__ int tsh[NPAIR];
  __shared__ int cnt_sh[NE];
  __shared__ int off_sh[NE + 1];
  const int tid = threadIdx.x;
  const int wave = tid >> 6;
  const int lane = tid & 63;

#pragma unroll
  for (int r = 0; r < NPAIR / 1024; ++r) tsh[r * 1024 + tid] = topi[r * 1024 + tid];
  __syncthreads();

  const int e = wave;
  int cnt = 0;
  for (int c = 0; c < NPAIR; c += 64) {
    unsigned long long msk = __ballot(tsh[c + lane] == e);
    cnt += __popcll(msk);
  }
  if (lane == 0) cnt_sh[e] = cnt;
  __syncthreads();
  if (tid == 0) {
    int acc = 0;
    for (int i = 0; i < NE; ++i) { off_sh[i] = acc; acc += cnt_sh[i]; }
    off_sh[NE] = acc;
  }
  __syncthreads();
  if (tid <= NE) offsets[tid] = off_sh[tid];

  int base = off_sh[e];
  for (int c = 0; c < NPAIR; c += 64) {
    bool match = (tsh[c + lane] == e);
    unsigned long long msk = __ballot(match);
    unsigned long long lt = (lane == 0) ? 0ull : ((~0ull) >> (64 - lane));
    int pre = __popcll(msk & lt);
    if (match) {
      int slot = base + pre;
      pair_token[slot] = (c + lane) >> 2;
      pair_weight[slot] = topv[c + lane];
    }
    base += __popcll(msk);
  }
}

// ---------- shared-expert activation: act = silu(gate) * up (bf16 in/out) ----------
__global__ __launch_bounds__(256) void act_kernel(const short* __restrict__ gub,
                                                  short* __restrict__ act) {
  int i = blockIdx.x * 256 + threadIdx.x;
  int t = i >> 8, g = i & 255;
  sh4 gs = *(const sh4*)(gub + (size_t)t * 2048 + g * 4);
  sh4 us = *(const sh4*)(gub + (size_t)t * 2048 + 1024 + g * 4);
  sh4 o;
#pragma unroll
  for (int q = 0; q < 4; ++q) {
    float gg = bf2f(gs[q]);
    float s = gg / (1.f + expf(-gg)) * bf2f(us[q]);
    o[q] = f2bf(s);
  }
  *(sh4*)(act + (size_t)t * 1024 + g * 4) = o;
}

// ---------- paired GEMM: counted-vmcnt pipeline + XOR bank swizzle ----------
// A bf16 via async16 (3-buffer ring, 2 iters ahead, swizzled SOURCE);
// B fp32 reg-staged -> bf16 ds_write (swizzled address), 1 iter ahead.
// PHASE 0: routed H1 (A=xb gathered, B=w1) + shared GU (A=xb, B=sgu N=2048)
// PHASE 1: routed Y (A=h1, B=w2, atomicAdd weighted) + shared DOWN (A=act, B=sdn)
template <int PHASE>
__global__ __launch_bounds__(256) void gemm_pair_kernel(
    const bf16* __restrict__ A_sh, const bf16* __restrict__ A_rt,
    const float* __restrict__ B_sh, const float* __restrict__ B_rt,
    void* __restrict__ O_sh, void* __restrict__ O_rt,
    const int* __restrict__ ptok, const float* __restrict__ pwt,
    const int* __restrict__ offsets) {
  __shared__ bf16 Ash[3][128][32];   // 24 KiB ring
  __shared__ bf16 Bsh[2][128][32];   // 16 KiB dbuf

  const int tid = threadIdx.x;
  const int lane = tid & 63;
  const int wave = tid >> 6;
  const int wm = wave >> 1, wn = wave & 1;

  const bool routed = (int)blockIdx.x < 2048;
  int mt, nt, seg_start = 0, count = 0;
  const bf16* Abase;
  const float* Bpanel;
  if (routed) {
    int bid = blockIdx.x;
    int e = bid & 15;
    int r = bid >> 4;
    mt = r >> 3; nt = r & 7;
    seg_start = offsets[e];
    count = offsets[e + 1] - seg_start;
    if (mt * 128 >= count) return;
    Abase = A_rt;
    Bpanel = B_rt + ((size_t)e << 20) + (size_t)(nt * 128) * KD;
  } else {
    int sb = blockIdx.x - 2048;
    constexpr int nwg = (PHASE == 0) ? 256 : 128;
    constexpr int cpx = nwg >> 3;
    int sw = (sb & 7) * cpx + (sb >> 3);
    nt = sw >> 4; mt = sw & 15;
    count = 1 << 30;
    Abase = A_sh;
    Bpanel = B_sh + (size_t)(nt * 128) * KD;
  }

  // A row pointers; global source pre-swizzled: 16B blk g = (lane&3) ^ ((lane>>3)&3)
  const int agsw = ((lane & 3) ^ ((lane >> 3) & 3)) * 8;
  const bf16* arow[2];
#pragma unroll
  for (int r = 0; r < 2; ++r) {
    int rowloc = r * 64 + wave * 16 + (lane >> 2);
    int grow;
    if (routed) {
      int slot = seg_start + mt * 128 + rowloc;
      if (slot > NPAIR - 1) slot = NPAIR - 1;
      grow = (PHASE == 0) ? ptok[slot] : slot;
    } else {
      grow = mt * 128 + rowloc;
    }
    arow[r] = Abase + (size_t)grow * KD + agsw;
  }

  // B row pointers (4 fv4/thread per K-step) + swizzled LDS write coords
  const float* brow[4];
  int bwrow[4], bwcol[4];
#pragma unroll
  for (int r = 0; r < 4; ++r) {
    int idx = (r << 8) + tid;
    int row = idx >> 3, cg = idx & 7;
    brow[r] = Bpanel + (size_t)row * KD + (cg << 2);
    int blkp = (cg >> 1) ^ ((row >> 1) & 3);
    bwrow[r] = row; bwcol[r] = blkp * 8 + (cg & 1) * 4;
  }

  // swizzled fragment read column (same for every mi/ni)
  const int rsw = ((lane & 15) >> 1) & 3;
  const int colsw = ((lane >> 4) ^ rsw) * 8;

  f4acc acc[4][4];
#pragma unroll
  for (int i = 0; i < 4; ++i)
#pragma unroll
    for (int j = 0; j < 4; ++j) acc[i][j] = (f4acc)(0.f);

  // ---- prologue: B(0) regs; A(0)->ring0, A(1)->ring1 ----
  {
    fv4 b0 = *(const fv4*)(brow[0]);
    fv4 b1 = *(const fv4*)(brow[1]);
    fv4 b2 = *(const fv4*)(brow[2]);
    fv4 b3 = *(const fv4*)(brow[3]);
    async16(arow[0],      (void*)&Ash[0][wave * 16][0]);
    async16(arow[1],      (void*)&Ash[0][64 + wave * 16][0]);
    async16(arow[0] + 32, (void*)&Ash[1][wave * 16][0]);
    async16(arow[1] + 32, (void*)&Ash[1][64 + wave * 16][0]);
    sh4 p0; p0[0]=f2bf(b0[0]); p0[1]=f2bf(b0[1]); p0[2]=f2bf(b0[2]); p0[3]=f2bf(b0[3]);
    sh4 p1; p1[0]=f2bf(b1[0]); p1[1]=f2bf(b1[1]); p1[2]=f2bf(b1[2]); p1[3]=f2bf(b1[3]);
    sh4 p2; p2[0]=f2bf(b2[0]); p2[1]=f2bf(b2[1]); p2[2]=f2bf(b2[2]); p2[3]=f2bf(b2[3]);
    sh4 p3; p3[0]=f2bf(b3[0]); p3[1]=f2bf(b3[1]); p3[2]=f2bf(b3[2]); p3[3]=f2bf(b3[3]);
    *(sh4*)&Bsh[0][bwrow[0]][bwcol[0]] = p0;
    *(sh4*)&Bsh[0][bwrow[1]][bwcol[1]] = p1;
    *(sh4*)&Bsh[0][bwrow[2]][bwcol[2]] = p2;
    *(sh4*)&Bsh[0][bwrow[3]][bwcol[3]] = p3;
    asm volatile("s_waitcnt vmcnt(2)" ::: "memory");          // A(0) landed; A(1) in flight
    asm volatile("s_waitcnt lgkmcnt(0)" ::: "memory");
    __builtin_amdgcn_sched_barrier(0);
    __builtin_amdgcn_s_barrier();
  }

  int c3 = 0;  // kt % 3
  for (int kt = 0; kt < 32; ++kt) {
    fv4 b0, b1, b2, b3;
    const bool hn = (kt < 31);
    if (hn) {
      const int kn1 = (kt + 1) * 32;
      b0 = *(const fv4*)(brow[0] + kn1);
      b1 = *(const fv4*)(brow[1] + kn1);
      b2 = *(const fv4*)(brow[2] + kn1);
      b3 = *(const fv4*)(brow[3] + kn1);
      if (kt < 30) {
        const int kn2 = (kt + 2) * 32;
        int a2 = c3 + 2; if (a2 >= 3) a2 -= 3;
        async16(arow[0] + kn2, (void*)&Ash[a2][wave * 16][0]);
        async16(arow[1] + kn2, (void*)&Ash[a2][64 + wave * 16][0]);
      }
    }
    __builtin_amdgcn_sched_barrier(0);  // keep issues above compute

    sh8 fa[4], fb[4];
#pragma unroll
    for (int mi = 0; mi < 4; ++mi)
      fa[mi] = *(const sh8*)&Ash[c3][wm * 64 + mi * 16 + (lane & 15)][colsw];
#pragma unroll
    for (int ni = 0; ni < 4; ++ni)
      fb[ni] = *(const sh8*)&Bsh[kt & 1][wn * 64 + ni * 16 + (lane & 15)][colsw];
#pragma unroll
    for (int mi = 0; mi < 4; ++mi)
#pragma unroll
      for (int ni = 0; ni < 4; ++ni)
        acc[mi][ni] = __builtin_amdgcn_mfma_f32_16x16x32_bf16(fa[mi], fb[ni], acc[mi][ni], 0, 0, 0);

    if (hn) {
      if (kt < 30) asm volatile("s_waitcnt vmcnt(2)" ::: "memory");   // B(kt+1)+A(kt+1) done
      else         asm volatile("s_waitcnt vmcnt(0)" ::: "memory");
      __builtin_amdgcn_sched_barrier(0);
      const int nb = (kt + 1) & 1;
      sh4 p0; p0[0]=f2bf(b0[0]); p0[1]=f2bf(b0[1]); p0[2]=f2bf(b0[2]); p0[3]=f2bf(b0[3]);
      sh4 p1; p1[0]=f2bf(b1[0]); p1[1]=f2bf(b1[1]); p1[2]=f2bf(b1[2]); p1[3]=f2bf(b1[3]);
      sh4 p2; p2[0]=f2bf(b2[0]); p2[1]=f2bf(b2[1]); p2[2]=f2bf(b2[2]); p2[3]=f2bf(b2[3]);
      sh4 p3; p3[0]=f2bf(b3[0]); p3[1]=f2bf(b3[1]); p3[2]=f2bf(b3[2]); p3[3]=f2bf(b3[3]);
      *(sh4*)&Bsh[nb][bwrow[0]][bwcol[0]] = p0;
      *(sh4*)&Bsh[nb][bwrow[1]][bwcol[1]] = p1;
      *(sh4*)&Bsh[nb][bwrow[2]][bwcol[2]] = p2;
      *(sh4*)&Bsh[nb][bwrow[3]][bwcol[3]] = p3;
      asm volatile("s_waitcnt lgkmcnt(0)" ::: "memory");
      __builtin_amdgcn_sched_barrier(0);
      __builtin_amdgcn_s_barrier();
    }
    c3 += 1; if (c3 == 3) c3 = 0;
  }

  // epilogue: C/D layout col = lane&15, row = (lane>>4)*4 + j
  if (PHASE == 0) {
    if (routed) {
#pragma unroll
      for (int mi = 0; mi < 4; ++mi) {
#pragma unroll
        for (int j = 0; j < 4; ++j) {
          int rloc = wm * 64 + mi * 16 + (lane >> 4) * 4 + j;
          if (mt * 128 + rloc >= count) continue;
          size_t orow = (size_t)(seg_start + mt * 128 + rloc) * 1024 + nt * 128;
#pragma unroll
          for (int ni = 0; ni < 4; ++ni) {
            int cloc = wn * 64 + ni * 16 + (lane & 15);
            float v = acc[mi][ni][j];
            float s = v / (1.f + expf(-v));
            ((short*)O_rt)[orow + cloc] = f2bf(s);
          }
        }
      }
    } else {
#pragma unroll
      for (int mi = 0; mi < 4; ++mi) {
#pragma unroll
        for (int j = 0; j < 4; ++j) {
          int rloc = wm * 64 + mi * 16 + (lane >> 4) * 4 + j;
          size_t orow = (size_t)(mt * 128 + rloc) * 2048 + nt * 128;
#pragma unroll
          for (int ni = 0; ni < 4; ++ni) {
            int cloc = wn * 64 + ni * 16 + (lane & 15);
            ((short*)O_sh)[orow + cloc] = f2bf(acc[mi][ni][j]);
          }
        }
      }
    }
  } else {
    if (routed) {
#pragma unroll
      for (int mi = 0; mi < 4; ++mi) {
#pragma unroll
        for (int j = 0; j < 4; ++j) {
          int rloc = wm * 64 + mi * 16 + (lane >> 4) * 4 + j;
          if (mt * 128 + rloc >= count) continue;
          int slot = seg_start + mt * 128 + rloc;
          int token = ptok[slot];
          float w = pwt[slot];
          float* orow = (float*)O_rt + (size_t)token * 1024 + nt * 128;
#pragma unroll
          for (int ni = 0; ni < 4; ++ni) {
            int cloc = wn * 64 + ni * 16 + (lane & 15);
            unsafeAtomicAdd(orow + cloc, w * acc[mi][ni][j]);
          }
        }
      }
    } else {
#pragma unroll
      for (int mi = 0; mi < 4; ++mi) {
#pragma unroll
        for (int j = 0; j < 4; ++j) {
          int rloc = wm * 64 + mi * 16 + (lane >> 4) * 4 + j;
          float* orow = (float*)O_sh + (size_t)(mt * 128 + rloc) * 1024 + nt * 128;
#pragma unroll
          for (int ni = 0; ni < 4; ++ni) {
            int cloc = wn * 64 + ni * 16 + (lane & 15);
            unsafeAtomicAdd(orow + cloc, acc[mi][ni][j]);
          }
        }
      }
    }
  }
}

extern "C" void kernel_launch(void* const* d_in, const int* in_sizes, int n_in,
                              void* d_out, int out_size, void* d_ws, size_t ws_size,
                              hipStream_t stream) {
  const float* x   = (const float*)d_in[0];
  const float* gw  = (const float*)d_in[1];
  const float* w1  = (const float*)d_in[2];
  const float* w2  = (const float*)d_in[3];
  const float* sgu = (const float*)d_in[4];
  const float* sdn = (const float*)d_in[5];
  float* out = (float*)d_out;

  char* ws = (char*)d_ws;
  bf16*  xb    = (bf16*)(ws + OFF_XB);
  bf16*  gub   = (bf16*)(ws + OFF_GUB);
  bf16*  act   = (bf16*)(ws + OFF_ACT);
  bf16*  h1    = (bf16*)(ws + OFF_H1);
  int*   topi  = (int*)(ws + OFF_TOPI);
  float* topv  = (float*)(ws + OFF_TOPV);
  int*   ptok  = (int*)(ws + OFF_PTOK);
  float* pwt   = (float*)(ws + OFF_PWT);
  int*   offs  = (int*)(ws + OFF_OFFS);

  hipMemsetAsync(d_out, 0, (size_t)out_size * sizeof(float), stream);

  cast_x_kernel<<<2048, 256, 0, stream>>>(x, xb);
  router_kernel<<<512, 256, 0, stream>>>(x, gw, topi, topv);
  route_build_kernel<<<1, 1024, 0, stream>>>(topi, topv, offs, ptok, pwt);

  // K2: routed H1 (blocks 0..2047) + shared GU (2048..2303)
  gemm_pair_kernel<0><<<2304, 256, 0, stream>>>(xb, xb, sgu, w1,
                                                gub, h1, ptok, pwt, offs);
  act_kernel<<<2048, 256, 0, stream>>>((const short*)gub, (short*)act);

  // K3: routed Y (0..2047) + shared DOWN (2048..2175); both atomicAdd into out
  gemm_pair_kernel<1><<<2176, 256, 0, stream>>>(act, h1, sdn, w2,
                                                out, out, ptok, pwt, offs);
}